// Round 19
// baseline (215.336 us; speedup 1.0000x reference)
//
#include <hip/hip_runtime.h>
#include <stdint.h>

// Problem constants
#define AA 144          // ATOM*ATOM
#define LAM 0.1f

// ---- workspace layout (float offsets) ----
#define OFS_SC    0            // 64 scalars: [16]=scX, [17]=scA
#define OFS_AF1   64           // 128*144 row-normalized zero-mean atoms
#define OFS_G     36928        // 128*128 gram (f32)
#define OFS_S0    53312        // ATB (bf16 atoms, [128][160] u16)
#define OFS_S1    69696        // ANTBP (bf16 atomsT, n-permuted, [144][128] u16)
#define OFS_X     86080        // XPB: bf16 X, k-permuted, [128][128] u16
#define OFS_PM    139328       // 32768 patch means
#define OFS_GOAL  172096       // 45056 goal (f32)
#define OFS_CF    4411456      // cfgb: packed bf16 pairs [32768][64] u32
#define OFS_PRED  8605760      // predh: bf16 [32768][144] u16
#define OFS_ATB   OFS_S0
#define OFS_ANTB  OFS_S1

// Contraction-dim permutation: real n = 32g + 16v + u  <->  stored ks = 32g + 2u + v.
// A and B sides both use stored order -> dot products unchanged.

typedef __attribute__((ext_vector_type(8))) short short8_t;
typedef __attribute__((ext_vector_type(4))) float f32x4;
typedef __attribute__((ext_vector_type(2))) float f32x2;

__device__ __forceinline__ unsigned short f2bf(float f) {      // RNE
    union { float f; uint32_t u; } x; x.f = f;
    uint32_t u = x.u;
    return (unsigned short)((u + 0x7FFFu + ((u >> 16) & 1u)) >> 16);
}
__device__ __forceinline__ unsigned short f2bh(float f) {      // round-half-up (cheap)
    union { float f; uint32_t u; } x; x.f = f;
    return (unsigned short)((x.u + 0x8000u) >> 16);
}
__device__ __forceinline__ float bf2f(unsigned short u) {
    union { float f; uint32_t i; } x; x.i = ((uint32_t)u) << 16; return x.f;
}
// pack two f32 -> packed bf16 pair (a->low, b->high), round-half-up
__device__ __forceinline__ uint32_t pack_bf(float a, float b) {
    union { float f; uint32_t u; } xa, xb; xa.f = a; xb.f = b;
    return __builtin_amdgcn_perm(xb.u + 0x8000u, xa.u + 0x8000u, 0x07060302u);
}

// ---- setup: block 0 = norm + bf16 gram + 8x power squarings + Rayleigh (1024 thr);
//      blocks 1..45 = goal copy + patch means (run hidden under block 0's chain). ----
#define PSTR 136
__global__ __launch_bounds__(1024) void k_setup(const float* atoms, const float* mu_p,
                                                float* ws, const float* y) {
    __shared__ unsigned short ABf[128 * 168];       // 43008 B
    __shared__ unsigned short Pb[2][128 * PSTR];    // 69632 B
    __shared__ float tr_arr[10];
    __shared__ float v[128];
    __shared__ float red[256];
    int t = threadIdx.x;
    if (blockIdx.x != 0) {                          // worker blocks: goal + pm
        int e = (blockIdx.x - 1) * 1024 + t;        // < 46080
        if (e < 45000) ws[OFS_GOAL + e] = y[e];
        if (e < 32768) {
            int b = e >> 12, pi = (e >> 6) & 63, pj = e & 63;
            const float* yb = y + b * 5625;
            float s = 0.f;
            for (int di = 0; di < 12; ++di) {
                const float* row = yb + (pi + di) * 75 + pj;
                #pragma unroll
                for (int dj = 0; dj < 12; ++dj) s += row[dj];
            }
            ws[OFS_PM + e] = s * (1.0f / 144.0f);
        }
        return;
    }
    int lane = t & 63, w = t >> 6;
    int col = lane & 15, quad = lane >> 4;
    if (t < 10) tr_arr[t] = (t == 0) ? 128.0f : 0.f;

    // ---- norm: 8 threads/atom, width-8 shfl reductions ----
    {
        int a = t >> 3, sub = t & 7;
        const float* ap = atoms + a * AA + sub * 18;
        float s = 0.f;
        #pragma unroll
        for (int k = 0; k < 18; ++k) s += ap[k];
        s += __shfl_xor(s, 1, 8); s += __shfl_xor(s, 2, 8); s += __shfl_xor(s, 4, 8);
        float mean = s * (1.0f / 144.0f);
        float ss = 0.f;
        #pragma unroll
        for (int k = 0; k < 18; ++k) { float d = ap[k] - mean; ss = fmaf(d, d, ss); }
        ss += __shfl_xor(ss, 1, 8); ss += __shfl_xor(ss, 2, 8); ss += __shfl_xor(ss, 4, 8);
        float rn = 1.0f / sqrtf(ss);
        #pragma unroll
        for (int k = 0; k < 18; ++k) {
            float av = (ap[k] - mean) * rn;
            ws[OFS_AF1 + a * AA + sub * 18 + k] = av;
            ABf[a * 168 + sub * 18 + k] = f2bf(av);
        }
        if (sub == 0) {
            #pragma unroll
            for (int k = AA; k < 160; ++k) ABf[a * 168 + k] = 0;
        }
    }
    __syncthreads();

    // ---- gram: wave w -> m-tile (w&7), g-half (w>>3) ----
    {
        uint32_t* D32 = (uint32_t*)Pb[0];
        float* G = ws + OFS_G;
        int mt = w & 7, gh = w >> 3;
        short8_t af[5];
        #pragma unroll
        for (int s = 0; s < 5; ++s)
            af[s] = *(const short8_t*)&ABf[(mt * 16 + col) * 168 + s * 32 + quad * 8];
        #pragma unroll
        for (int gi = 0; gi < 2; ++gi) {
            int g = gh * 2 + gi;
            short8_t b0[5], b1[5];
            #pragma unroll
            for (int s = 0; s < 5; ++s) {
                b0[s] = *(const short8_t*)&ABf[((2 * g) * 16 + col) * 168 + s * 32 + quad * 8];
                b1[s] = *(const short8_t*)&ABf[((2 * g + 1) * 16 + col) * 168 + s * 32 + quad * 8];
            }
            f32x4 a0 = (f32x4){0.f, 0.f, 0.f, 0.f};
            f32x4 a1 = (f32x4){0.f, 0.f, 0.f, 0.f};
            #pragma unroll
            for (int s = 0; s < 5; ++s) {
                a0 = __builtin_amdgcn_mfma_f32_16x16x32_bf16(af[s], b0[s], a0, 0, 0, 0);
                a1 = __builtin_amdgcn_mfma_f32_16x16x32_bf16(af[s], b1[s], a1, 0, 0, 0);
            }
            #pragma unroll
            for (int r = 0; r < 4; ++r) {
                int m = mt * 16 + quad * 4 + r;
                G[m * 128 + g * 32 + col] = a0[r];
                G[m * 128 + g * 32 + 16 + col] = a1[r];
                D32[m * 68 + g * 16 + col] = pack_bf(a0[r], a1[r]);
            }
        }
    }
    __syncthreads();

    // ---- power: 8 squarings; wave w -> m-tile (w&7), n-quarter (w>>3) ----
    int cur = 0;
    #pragma unroll 1
    for (int j = 0; j < 8; ++j) {
        float trn = tr_arr[j];
        float inv2 = 1.0f / (trn * trn);
        const unsigned short* S = Pb[cur];
        uint32_t* D32 = (uint32_t*)Pb[cur ^ 1];
        int mt = w & 7, nh = w >> 3;
        short8_t af[4];
        #pragma unroll
        for (int s = 0; s < 4; ++s)
            af[s] = *(const short8_t*)&S[(mt * 16 + col) * PSTR + s * 32 + quad * 8];
        #pragma unroll
        for (int pr = 0; pr < 2; ++pr) {
            int ntE = 4 * nh + 2 * pr, ntO = ntE + 1;
            short8_t bE[4], bO[4];
            #pragma unroll
            for (int s = 0; s < 4; ++s) {
                bE[s] = *(const short8_t*)&S[(ntE * 16 + col) * PSTR + s * 32 + quad * 8];
                bO[s] = *(const short8_t*)&S[(ntO * 16 + col) * PSTR + s * 32 + quad * 8];
            }
            f32x4 aE = (f32x4){0.f, 0.f, 0.f, 0.f};
            f32x4 aO = (f32x4){0.f, 0.f, 0.f, 0.f};
            #pragma unroll
            for (int s = 0; s < 4; ++s) {
                aE = __builtin_amdgcn_mfma_f32_16x16x32_bf16(af[s], bE[s], aE, 0, 0, 0);
                aO = __builtin_amdgcn_mfma_f32_16x16x32_bf16(af[s], bO[s], aO, 0, 0, 0);
            }
            int nE = ntE * 16 + col, nO = ntO * 16 + col;
            #pragma unroll
            for (int r = 0; r < 4; ++r) {
                float x0 = aE[r] * inv2, x1 = aO[r] * inv2;
                int row = mt * 16 + quad * 4 + r;
                D32[row * 68 + (ntE >> 1) * 16 + col] = pack_bf(x0, x1);
                if (row == nE) atomicAdd(&tr_arr[j + 1], x0);
                if (row == nO) atomicAdd(&tr_arr[j + 1], x1);
            }
        }
        __syncthreads();
        cur ^= 1;
    }

    // ---- Rayleigh on f32 G (8 threads/row) ----
    {
        int a = t >> 3, sub = t & 7;
        const unsigned short* S = Pb[cur];
        float s = 0.f;
        #pragma unroll
        for (int k = 0; k < 16; ++k) s += bf2f(S[a * PSTR + sub * 16 + k]);
        s += __shfl_xor(s, 1, 8); s += __shfl_xor(s, 2, 8); s += __shfl_xor(s, 4, 8);
        if (sub == 0) v[a] = s;
    }
    __syncthreads();
    {
        int a = t >> 3, sub = t & 7;
        const float* G = ws + OFS_G;
        float wv = 0.f;
        #pragma unroll
        for (int k = 0; k < 16; ++k)
            wv = fmaf(G[a * 128 + sub * 16 + k], v[sub * 16 + k], wv);
        wv += __shfl_xor(wv, 1, 8); wv += __shfl_xor(wv, 2, 8); wv += __shfl_xor(wv, 4, 8);
        if (sub == 0) { red[a] = v[a] * wv; red[128 + a] = v[a] * v[a]; }
    }
    __syncthreads();
    for (int off = 64; off > 0; off >>= 1) {
        if (t < off) { red[t] += red[t + off]; red[128 + t] += red[128 + t + off]; }
        __syncthreads();
    }
    if (t == 0) {
        float lam = red[0] / red[128];
        float mu = fmaxf(mu_p[0], 0.0f);
        ws[OFS_SC + 16] = 1.0f / (lam * mu);
        ws[OFS_SC + 17] = 1.0f / (sqrtf(lam) * sqrtf(mu));
    }
}

// ---- finalize: only the scale-dependent tables (XPB / ATB / ANTBP) ----
__global__ __launch_bounds__(256) void k_finalize(float* ws) {
    int idx = blockIdx.x * 256 + threadIdx.x;       // grid 216 -> 55296
    float scX = ws[OFS_SC + 16], scA = ws[OFS_SC + 17];
    if (idx < 16384) {
        int n = idx >> 7, ks = idx & 127;
        int g = ks >> 5, rem = ks & 31, u = rem >> 1, v = rem & 1;
        int k = g * 32 + v * 16 + u;
        ((unsigned short*)(ws + OFS_X))[idx] = f2bf(ws[OFS_G + n * 128 + k] * scX);
    } else if (idx < 36864) {
        int e = idx - 16384;                        // ATB [n=128][k=160] zero-pad
        int n = e / 160, k = e - n * 160;
        float v = (k < 144) ? ws[OFS_AF1 + n * 144 + k] * scA : 0.f;
        ((unsigned short*)(ws + OFS_ATB))[e] = f2bf(v);
    } else {
        int e = idx - 36864;                        // ANTBP [j=144][ks=128]
        int jp = e >> 7, ks = e & 127;
        int g = ks >> 5, rem = ks & 31, u = rem >> 1, v = rem & 1;
        int n = g * 32 + v * 16 + u;
        ((unsigned short*)(ws + OFS_ANTB))[e] = f2bf(ws[OFS_AF1 + n * 144 + jp] * scA);
    }
}

// ---- fused megakernel: 16 patches/block (grid 2048 -> ~7-8 blocks/CU co-resident).
//      Wave w: mt=1 (16 patches) x nt=2 (cols 32w..32w+31). LDS union = 8704 B. ----
__global__ __launch_bounds__(256) void k_fista(const unsigned short* XPB, const float* goal,
                                               const unsigned short* ATB,
                                               const unsigned short* ANTBP,
                                               const float* pm, uint32_t* cfgb,
                                               unsigned short* predh,
                                               const float* mu_p, int first, int write_cf) {
    __shared__ union __align__(16) {
        unsigned short Atile[16 * 168];            // 5376 B (q phase)
        unsigned short Zbuf[2][16 * 136];          // 8704 B (FISTA phase)
    } sm;
    int t = threadIdx.x;
    int lane = t & 63, w = t >> 6;
    int col = lane & 15, quad = lane >> 4;
    int nb = w * 32;
    int blk = blockIdx.x;                          // 2048 = b(8) x pi(64) x h(4)
    int b = blk >> 8, pi = (blk >> 2) & 63, h = blk & 3;
    int p0 = blk * 16;
    float mu = fmaxf(mu_p[0], 0.0f);
    const f32x2 mu2 = (f32x2){mu, mu};
    const f32x2 lam2 = (f32x2){LAM, LAM};
    const f32x2 nlam2 = (f32x2){-LAM, -LAM};

    // ---- im2col A-tile 16 x 160 bf16 directly from goal (max col = 48+15+11 = 74) ----
    {
        const float* gb = goal + b * 5625 + pi * 75 + h * 16;
        uint32_t* A32 = (uint32_t*)sm.Atile;       // row stride 84 u32
        #pragma unroll
        for (int i = 0; i < 5; ++i) {
            int pe = t + i * 256;                  // < 1280 = 16m * 80 pairs
            int m = pe / 80, q32 = pe - m * 80;
            int kk = q32 * 2;
            float v0 = 0.f, v1 = 0.f;
            if (kk < 144) {
                int di = kk / 12, dj = kk - di * 12;
                v0 = gb[di * 75 + m + dj];
                int k1 = kk + 1, di1 = k1 / 12, dj1 = k1 - di1 * 12;
                v1 = gb[di1 * 75 + m + dj1];
            }
            A32[m * 84 + q32] = pack_bf(v0, v1);
        }
    }
    __syncthreads();

    // ---- q-matmul: qv2[r] = {q(nt0), q(nt1)} in C/D layout ----
    f32x2 qv2[4];
    {
        short8_t bfq[2][5];
        #pragma unroll
        for (int nt = 0; nt < 2; ++nt)
            #pragma unroll
            for (int s = 0; s < 5; ++s)
                bfq[nt][s] = *(const short8_t*)&ATB[(nb + nt * 16 + col) * 160 + s * 32 + quad * 8];
        short8_t af[5];
        #pragma unroll
        for (int s = 0; s < 5; ++s)
            af[s] = *(const short8_t*)&sm.Atile[col * 168 + s * 32 + quad * 8];
        f32x4 acc0 = (f32x4){0.f, 0.f, 0.f, 0.f};
        f32x4 acc1 = (f32x4){0.f, 0.f, 0.f, 0.f};
        #pragma unroll
        for (int s = 0; s < 5; ++s) {
            acc0 = __builtin_amdgcn_mfma_f32_16x16x32_bf16(af[s], bfq[0][s], acc0, 0, 0, 0);
            acc1 = __builtin_amdgcn_mfma_f32_16x16x32_bf16(af[s], bfq[1][s], acc1, 0, 0, 0);
        }
        #pragma unroll
        for (int r = 0; r < 4; ++r) qv2[r] = (f32x2){acc0[r], acc1[r]};
    }
    __syncthreads();                               // Atile dead; Zbuf may now alias it

    // ---- X B-fragments: contiguous b128 from pre-permuted bf16 XPB ----
    short8_t xf[2][4];
    #pragma unroll
    for (int nt = 0; nt < 2; ++nt)
        #pragma unroll
        for (int s = 0; s < 4; ++s)
            xf[nt][s] = *(const short8_t*)&XPB[(nb + nt * 16 + col) * 128 + s * 32 + quad * 8];

    // ---- c0 / z0 init, seed Z (packed bf16 pairs from cfgb) ----
    uint32_t* Z32w = (uint32_t*)sm.Zbuf[0];        // row stride 68 u32
    f32x2 cv2[4], zo2[4];
    #pragma unroll
    for (int r = 0; r < 4; ++r) {
        int row = quad * 4 + r;
        uint32_t pk = 0u;
        float c0 = 0.f, c1 = 0.f;
        if (!first) {
            pk = cfgb[(p0 + row) * 64 + 16 * w + col];
            c0 = bf2f((unsigned short)(pk & 0xFFFFu));
            c1 = bf2f((unsigned short)(pk >> 16));
        }
        cv2[r] = (f32x2){c0, c1};
        zo2[r] = (f32x2){c0, c1};
        Z32w[row * 68 + 16 * w + col] = pk;
    }
    __syncthreads();

    f32x4 acc[2];
    auto matmul = [&](const unsigned short* Zr) {
        short8_t af[4];
        #pragma unroll
        for (int s = 0; s < 4; ++s)
            af[s] = *(const short8_t*)&Zr[col * 136 + s * 32 + quad * 8];
        acc[0] = (f32x4){0.f, 0.f, 0.f, 0.f};
        acc[1] = (f32x4){0.f, 0.f, 0.f, 0.f};
        #pragma unroll
        for (int s = 0; s < 4; ++s) {
            acc[0] = __builtin_amdgcn_mfma_f32_16x16x32_bf16(af[s], xf[0][s], acc[0], 0, 0, 0);
            acc[1] = __builtin_amdgcn_mfma_f32_16x16x32_bf16(af[s], xf[1][s], acc[1], 0, 0, 0);
        }
    };

    float tm = 1.0f;
    int cur = 0;
    #pragma unroll 1
    for (int it = 0; it < 14; ++it) {          // FISTA iters 1..14 (write z)
        matmul(sm.Zbuf[cur]);
        float tnn = 0.5f * (1.0f + sqrtf(1.0f + 4.0f * tm * tm));
        float fm = (tm - 1.0f) / tnn;
        tm = tnn;
        f32x2 fm2 = (f32x2){fm, fm};
        uint32_t* Zw = (uint32_t*)sm.Zbuf[cur ^ 1];
        #pragma unroll
        for (int r = 0; r < 4; ++r) {
            f32x2 a2 = (f32x2){acc[0][r], acc[1][r]};
            f32x2 u2 = mu2 * (qv2[r] - a2) + zo2[r];
            f32x2 cl2 = __builtin_elementwise_min(
                            __builtin_elementwise_max(u2, nlam2), lam2);
            f32x2 cn2 = u2 - cl2;
            f32x2 zn2 = fm2 * (cn2 - cv2[r]) + cn2;
            cv2[r] = cn2;
            zo2[r] = zn2;
            Zw[(quad * 4 + r) * 68 + 16 * w + col] = pack_bf(zn2[0], zn2[1]);
        }
        __syncthreads();
        cur ^= 1;
    }
    {   // FISTA iter 15: compute c15; stage c15 (z15 never consumed)
        matmul(sm.Zbuf[cur]);
        uint32_t* Zw = (uint32_t*)sm.Zbuf[cur ^ 1];
        #pragma unroll
        for (int r = 0; r < 4; ++r) {
            f32x2 a2 = (f32x2){acc[0][r], acc[1][r]};
            f32x2 u2 = mu2 * (qv2[r] - a2) + zo2[r];
            f32x2 cl2 = __builtin_elementwise_min(
                            __builtin_elementwise_max(u2, nlam2), lam2);
            f32x2 cn2 = u2 - cl2;
            cv2[r] = cn2;
            Zw[(quad * 4 + r) * 68 + 16 * w + col] = pack_bf(cn2[0], cn2[1]);
        }
        __syncthreads();
        cur ^= 1;
    }
    {   // final differentiable step: cf = prox(c15 + mu*(q - X@c15)); stage cf
        matmul(sm.Zbuf[cur]);
        uint32_t* Zw = (uint32_t*)sm.Zbuf[cur ^ 1];
        #pragma unroll
        for (int r = 0; r < 4; ++r) {
            int row = quad * 4 + r;
            f32x2 a2 = (f32x2){acc[0][r], acc[1][r]};
            f32x2 u2 = mu2 * (qv2[r] - a2) + cv2[r];
            f32x2 cl2 = __builtin_elementwise_min(
                            __builtin_elementwise_max(u2, nlam2), lam2);
            f32x2 cf2 = u2 - cl2;
            uint32_t pk = pack_bf(cf2[0], cf2[1]);
            if (write_cf) cfgb[(p0 + row) * 64 + 16 * w + col] = pk;
            Zw[row * 68 + 16 * w + col] = pk;
        }
        __syncthreads();
        cur ^= 1;
    }

    // ---- pred tail: predh[16][144] = bf16(cf @ atoms_n + pm); j-tiles 3/2/2/2 ----
    {
        int jt0 = (w == 0) ? 0 : (2 * w + 1);
        int jtn = (w == 0) ? 3 : 2;
        const unsigned short* Zr = sm.Zbuf[cur];
        short8_t af[4];
        #pragma unroll
        for (int s = 0; s < 4; ++s)
            af[s] = *(const short8_t*)&Zr[col * 136 + s * 32 + quad * 8];
        f32x4 accp[3];
        #pragma unroll
        for (int ji = 0; ji < 3; ++ji) accp[ji] = (f32x4){0.f, 0.f, 0.f, 0.f};
        #pragma unroll
        for (int ji = 0; ji < 3; ++ji) {
            if (ji < jtn) {
                int jt = jt0 + ji;
                #pragma unroll
                for (int s = 0; s < 4; ++s) {
                    short8_t bf4 = *(const short8_t*)&ANTBP[(jt * 16 + col) * 128 + s * 32 + quad * 8];
                    accp[ji] = __builtin_amdgcn_mfma_f32_16x16x32_bf16(af[s], bf4, accp[ji], 0, 0, 0);
                }
            }
        }
        #pragma unroll
        for (int r = 0; r < 4; ++r) {
            int p = p0 + quad * 4 + r;
            float pmv = pm[p];
            #pragma unroll
            for (int ji = 0; ji < 3; ++ji)
                if (ji < jtn)
                    predh[p * 144 + (jt0 + ji) * 16 + col] = f2bh(accp[ji][r] + pmv);
        }
    }
}

// ---- fold via LDS staging: block = (output row i, batch b); bf16 pred reads. ----
__global__ __launch_bounds__(256) void k_fold(const float* y, const float* beta_p,
                                              const unsigned short* predh, float* goal,
                                              float* out, int write_out) {
    __shared__ float P[12 * 832];              // 39,936 B
    int i = blockIdx.x, b = blockIdx.y;
    int t = threadIdx.x;
    for (int di = 0; di < 12; ++di) {
        int pi = i - di;
        if ((unsigned)pi >= 64u) continue;     // uniform per block
        int base = (b << 12) + (pi << 6);
        #pragma unroll
        for (int it = 0; it < 3; ++it) {
            int e = t + it * 256;              // < 768 = 64 pj * 12 dj
            int pj = e / 12, dj = e - pj * 12;
            P[di * 832 + pj * 13 + dj] = bf2f(predh[(base + pj) * AA + di * 12 + dj]);
        }
    }
    __syncthreads();
    if (t >= 75) return;
    int j = t;
    float S = 0.f;
    for (int di = 0; di < 12; ++di) {
        if ((unsigned)(i - di) >= 64u) continue;
        const float* Pd = &P[di * 832];
        #pragma unroll
        for (int dj = 0; dj < 12; ++dj) {
            int pj = j - dj;
            if ((unsigned)pj >= 64u) continue;
            S += Pd[pj * 13 + dj];
        }
    }
    int ci = min(i, 11) - max(i - 63, 0) + 1;
    int cj = min(j, 11) - max(j - 63, 0) + 1;
    float beta = fmaxf(beta_p[0], 0.0f);
    int idx = i * 75 + j;
    float yv = y[b * 5625 + idx];
    float g = (yv + beta * S) / (1.0f + beta * (float)(ci * cj));
    if (write_out) out[b * 5625 + idx] = g;
    else           goal[b * 5625 + idx] = g;
}

extern "C" void kernel_launch(void* const* d_in, const int* in_sizes, int n_in,
                              void* d_out, int out_size, void* d_ws, size_t ws_size,
                              hipStream_t stream) {
    const float* y     = (const float*)d_in[0];
    const float* atoms = (const float*)d_in[1];
    const float* beta  = (const float*)d_in[2];
    const float* mu    = (const float*)d_in[3];
    float* out = (float*)d_out;
    float* ws = (float*)d_ws;

    k_setup<<<46, 1024, 0, stream>>>(atoms, mu, ws, y);   // block0 chain + workers goal/pm
    k_finalize<<<216, 256, 0, stream>>>(ws);              // XPB + ATB + ANTBP

    for (int u = 0; u < 2; ++u) {
        k_fista<<<2048, 256, 0, stream>>>((const unsigned short*)(ws + OFS_X),
                                          ws + OFS_GOAL,
                                          (const unsigned short*)(ws + OFS_ATB),
                                          (const unsigned short*)(ws + OFS_ANTB),
                                          ws + OFS_PM, (uint32_t*)(ws + OFS_CF),
                                          (unsigned short*)(ws + OFS_PRED),
                                          mu, u == 0 ? 1 : 0, u == 0 ? 1 : 0);
        k_fold<<<dim3(75, 8), 256, 0, stream>>>(y, beta,
                                                (const unsigned short*)(ws + OFS_PRED),
                                                ws + OFS_GOAL, out, u == 1 ? 1 : 0);
    }
}

// Round 20
// 213.583 us; speedup vs baseline: 1.0082x; 1.0082x over previous
//
#include <hip/hip_runtime.h>
#include <stdint.h>

// Problem constants
#define AA 144          // ATOM*ATOM
#define LAM 0.1f

// ---- workspace layout (float offsets) ----
#define OFS_SC    0            // 64 scalars: [16]=scX, [17]=scA
#define OFS_AF1   64           // 128*144 row-normalized zero-mean atoms
#define OFS_G     36928        // 128*128 gram (f32)
#define OFS_S0    53312        // ATB (bf16 atoms, [128][160] u16)
#define OFS_S1    69696        // ANTBP (bf16 atomsT, n-permuted, [144][128] u16)
#define OFS_X     86080        // XPB: bf16 X, k-permuted, [128][128] u16
#define OFS_PM    139328       // 32768 patch means
#define OFS_GOAL  172096       // 45056 goal (f32)
#define OFS_CF    4411456      // cfgb: packed bf16 pairs [32768][64] u32
#define OFS_PRED  8605760      // predh: bf16 [32768][144] u16
#define OFS_ATB   OFS_S0
#define OFS_ANTB  OFS_S1

// Contraction-dim permutation: real n = 32g + 16v + u  <->  stored ks = 32g + 2u + v.
// A and B sides both use stored order -> dot products unchanged.

typedef __attribute__((ext_vector_type(8))) short short8_t;
typedef __attribute__((ext_vector_type(4))) float f32x4;
typedef __attribute__((ext_vector_type(2))) float f32x2;

__device__ __forceinline__ unsigned short f2bf(float f) {      // RNE
    union { float f; uint32_t u; } x; x.f = f;
    uint32_t u = x.u;
    return (unsigned short)((u + 0x7FFFu + ((u >> 16) & 1u)) >> 16);
}
__device__ __forceinline__ unsigned short f2bh(float f) {      // round-half-up (cheap)
    union { float f; uint32_t u; } x; x.f = f;
    return (unsigned short)((x.u + 0x8000u) >> 16);
}
__device__ __forceinline__ float bf2f(unsigned short u) {
    union { float f; uint32_t i; } x; x.i = ((uint32_t)u) << 16; return x.f;
}
// pack two f32 -> packed bf16 pair (a->low, b->high), round-half-up
__device__ __forceinline__ uint32_t pack_bf(float a, float b) {
    union { float f; uint32_t u; } xa, xb; xa.f = a; xb.f = b;
    return __builtin_amdgcn_perm(xb.u + 0x8000u, xa.u + 0x8000u, 0x07060302u);
}

// ---- setup: block 0 = norm + bf16 gram + 8x power squarings + Rayleigh (1024 thr);
//      blocks 1..45 = goal copy + patch means (run hidden under block 0's chain). ----
#define PSTR 136
__global__ __launch_bounds__(1024) void k_setup(const float* atoms, const float* mu_p,
                                                float* ws, const float* y) {
    __shared__ unsigned short ABf[128 * 168];       // 43008 B
    __shared__ unsigned short Pb[2][128 * PSTR];    // 69632 B
    __shared__ float tr_arr[10];
    __shared__ float v[128];
    __shared__ float red[256];
    int t = threadIdx.x;
    if (blockIdx.x != 0) {                          // worker blocks: goal + pm
        int e = (blockIdx.x - 1) * 1024 + t;        // < 46080
        if (e < 45000) ws[OFS_GOAL + e] = y[e];
        if (e < 32768) {
            int b = e >> 12, pi = (e >> 6) & 63, pj = e & 63;
            const float* yb = y + b * 5625;
            float s = 0.f;
            for (int di = 0; di < 12; ++di) {
                const float* row = yb + (pi + di) * 75 + pj;
                #pragma unroll
                for (int dj = 0; dj < 12; ++dj) s += row[dj];
            }
            ws[OFS_PM + e] = s * (1.0f / 144.0f);
        }
        return;
    }
    int lane = t & 63, w = t >> 6;
    int col = lane & 15, quad = lane >> 4;
    if (t < 10) tr_arr[t] = (t == 0) ? 128.0f : 0.f;

    // ---- norm: 8 threads/atom, width-8 shfl reductions ----
    {
        int a = t >> 3, sub = t & 7;
        const float* ap = atoms + a * AA + sub * 18;
        float s = 0.f;
        #pragma unroll
        for (int k = 0; k < 18; ++k) s += ap[k];
        s += __shfl_xor(s, 1, 8); s += __shfl_xor(s, 2, 8); s += __shfl_xor(s, 4, 8);
        float mean = s * (1.0f / 144.0f);
        float ss = 0.f;
        #pragma unroll
        for (int k = 0; k < 18; ++k) { float d = ap[k] - mean; ss = fmaf(d, d, ss); }
        ss += __shfl_xor(ss, 1, 8); ss += __shfl_xor(ss, 2, 8); ss += __shfl_xor(ss, 4, 8);
        float rn = 1.0f / sqrtf(ss);
        #pragma unroll
        for (int k = 0; k < 18; ++k) {
            float av = (ap[k] - mean) * rn;
            ws[OFS_AF1 + a * AA + sub * 18 + k] = av;
            ABf[a * 168 + sub * 18 + k] = f2bf(av);
        }
        if (sub == 0) {
            #pragma unroll
            for (int k = AA; k < 160; ++k) ABf[a * 168 + k] = 0;
        }
    }
    __syncthreads();

    // ---- gram: wave w -> m-tile (w&7), g-half (w>>3) ----
    {
        uint32_t* D32 = (uint32_t*)Pb[0];
        float* G = ws + OFS_G;
        int mt = w & 7, gh = w >> 3;
        short8_t af[5];
        #pragma unroll
        for (int s = 0; s < 5; ++s)
            af[s] = *(const short8_t*)&ABf[(mt * 16 + col) * 168 + s * 32 + quad * 8];
        #pragma unroll
        for (int gi = 0; gi < 2; ++gi) {
            int g = gh * 2 + gi;
            short8_t b0[5], b1[5];
            #pragma unroll
            for (int s = 0; s < 5; ++s) {
                b0[s] = *(const short8_t*)&ABf[((2 * g) * 16 + col) * 168 + s * 32 + quad * 8];
                b1[s] = *(const short8_t*)&ABf[((2 * g + 1) * 16 + col) * 168 + s * 32 + quad * 8];
            }
            f32x4 a0 = (f32x4){0.f, 0.f, 0.f, 0.f};
            f32x4 a1 = (f32x4){0.f, 0.f, 0.f, 0.f};
            #pragma unroll
            for (int s = 0; s < 5; ++s) {
                a0 = __builtin_amdgcn_mfma_f32_16x16x32_bf16(af[s], b0[s], a0, 0, 0, 0);
                a1 = __builtin_amdgcn_mfma_f32_16x16x32_bf16(af[s], b1[s], a1, 0, 0, 0);
            }
            #pragma unroll
            for (int r = 0; r < 4; ++r) {
                int m = mt * 16 + quad * 4 + r;
                G[m * 128 + g * 32 + col] = a0[r];
                G[m * 128 + g * 32 + 16 + col] = a1[r];
                D32[m * 68 + g * 16 + col] = pack_bf(a0[r], a1[r]);
            }
        }
    }
    __syncthreads();

    // ---- power: 8 squarings; wave w -> m-tile (w&7), n-quarter (w>>3) ----
    int cur = 0;
    #pragma unroll 1
    for (int j = 0; j < 8; ++j) {
        float trn = tr_arr[j];
        float inv2 = 1.0f / (trn * trn);
        const unsigned short* S = Pb[cur];
        uint32_t* D32 = (uint32_t*)Pb[cur ^ 1];
        int mt = w & 7, nh = w >> 3;
        short8_t af[4];
        #pragma unroll
        for (int s = 0; s < 4; ++s)
            af[s] = *(const short8_t*)&S[(mt * 16 + col) * PSTR + s * 32 + quad * 8];
        #pragma unroll
        for (int pr = 0; pr < 2; ++pr) {
            int ntE = 4 * nh + 2 * pr, ntO = ntE + 1;
            short8_t bE[4], bO[4];
            #pragma unroll
            for (int s = 0; s < 4; ++s) {
                bE[s] = *(const short8_t*)&S[(ntE * 16 + col) * PSTR + s * 32 + quad * 8];
                bO[s] = *(const short8_t*)&S[(ntO * 16 + col) * PSTR + s * 32 + quad * 8];
            }
            f32x4 aE = (f32x4){0.f, 0.f, 0.f, 0.f};
            f32x4 aO = (f32x4){0.f, 0.f, 0.f, 0.f};
            #pragma unroll
            for (int s = 0; s < 4; ++s) {
                aE = __builtin_amdgcn_mfma_f32_16x16x32_bf16(af[s], bE[s], aE, 0, 0, 0);
                aO = __builtin_amdgcn_mfma_f32_16x16x32_bf16(af[s], bO[s], aO, 0, 0, 0);
            }
            int nE = ntE * 16 + col, nO = ntO * 16 + col;
            #pragma unroll
            for (int r = 0; r < 4; ++r) {
                float x0 = aE[r] * inv2, x1 = aO[r] * inv2;
                int row = mt * 16 + quad * 4 + r;
                D32[row * 68 + (ntE >> 1) * 16 + col] = pack_bf(x0, x1);
                if (row == nE) atomicAdd(&tr_arr[j + 1], x0);
                if (row == nO) atomicAdd(&tr_arr[j + 1], x1);
            }
        }
        __syncthreads();
        cur ^= 1;
    }

    // ---- Rayleigh on f32 G (8 threads/row) ----
    {
        int a = t >> 3, sub = t & 7;
        const unsigned short* S = Pb[cur];
        float s = 0.f;
        #pragma unroll
        for (int k = 0; k < 16; ++k) s += bf2f(S[a * PSTR + sub * 16 + k]);
        s += __shfl_xor(s, 1, 8); s += __shfl_xor(s, 2, 8); s += __shfl_xor(s, 4, 8);
        if (sub == 0) v[a] = s;
    }
    __syncthreads();
    {
        int a = t >> 3, sub = t & 7;
        const float* G = ws + OFS_G;
        float wv = 0.f;
        #pragma unroll
        for (int k = 0; k < 16; ++k)
            wv = fmaf(G[a * 128 + sub * 16 + k], v[sub * 16 + k], wv);
        wv += __shfl_xor(wv, 1, 8); wv += __shfl_xor(wv, 2, 8); wv += __shfl_xor(wv, 4, 8);
        if (sub == 0) { red[a] = v[a] * wv; red[128 + a] = v[a] * v[a]; }
    }
    __syncthreads();
    for (int off = 64; off > 0; off >>= 1) {
        if (t < off) { red[t] += red[t + off]; red[128 + t] += red[128 + t + off]; }
        __syncthreads();
    }
    if (t == 0) {
        float lam = red[0] / red[128];
        float mu = fmaxf(mu_p[0], 0.0f);
        ws[OFS_SC + 16] = 1.0f / (lam * mu);
        ws[OFS_SC + 17] = 1.0f / (sqrtf(lam) * sqrtf(mu));
    }
}

// ---- finalize: only the scale-dependent tables (XPB / ATB / ANTBP) ----
__global__ __launch_bounds__(256) void k_finalize(float* ws) {
    int idx = blockIdx.x * 256 + threadIdx.x;       // grid 216 -> 55296
    float scX = ws[OFS_SC + 16], scA = ws[OFS_SC + 17];
    if (idx < 16384) {
        int n = idx >> 7, ks = idx & 127;
        int g = ks >> 5, rem = ks & 31, u = rem >> 1, v = rem & 1;
        int k = g * 32 + v * 16 + u;
        ((unsigned short*)(ws + OFS_X))[idx] = f2bf(ws[OFS_G + n * 128 + k] * scX);
    } else if (idx < 36864) {
        int e = idx - 16384;                        // ATB [n=128][k=160] zero-pad
        int n = e / 160, k = e - n * 160;
        float v = (k < 144) ? ws[OFS_AF1 + n * 144 + k] * scA : 0.f;
        ((unsigned short*)(ws + OFS_ATB))[e] = f2bf(v);
    } else {
        int e = idx - 36864;                        // ANTBP [j=144][ks=128]
        int jp = e >> 7, ks = e & 127;
        int g = ks >> 5, rem = ks & 31, u = rem >> 1, v = rem & 1;
        int n = g * 32 + v * 16 + u;
        ((unsigned short*)(ws + OFS_ANTB))[e] = f2bf(ws[OFS_AF1 + n * 144 + jp] * scA);
    }
}

// ---- fused megakernel: q (im2col MFMA, direct-from-goal) + FISTA(15)+1 + pred(bf16).
//      cfg as packed bf16 pairs (u32) between unrolls. (R18 champion) ----
__global__ __launch_bounds__(256) void k_fista(const unsigned short* XPB, const float* goal,
                                               const unsigned short* ATB,
                                               const unsigned short* ANTBP,
                                               const float* pm, uint32_t* cfgb,
                                               unsigned short* predh,
                                               const float* mu_p, int first, int write_cf) {
    __shared__ unsigned short Atile[32 * 168];
    __shared__ unsigned short Zbuf[2][32 * 136];
    int t = threadIdx.x;
    int lane = t & 63, w = t >> 6;
    int col = lane & 15, quad = lane >> 4;
    int nb = w * 32;
    int blk = blockIdx.x;
    int b = blk >> 7, pi = (blk >> 1) & 63, h = blk & 1;
    int p0 = blk * 32;
    float mu = fmaxf(mu_p[0], 0.0f);
    const f32x2 mu2 = (f32x2){mu, mu};
    const f32x2 lam2 = (f32x2){LAM, LAM};
    const f32x2 nlam2 = (f32x2){-LAM, -LAM};

    // ---- im2col A-tile 32 x 160 bf16 directly from goal (no staging; max col
    //      = 32+31+11 = 74 < 75, so no bounds check needed) ----
    {
        const float* gb = goal + b * 5625 + pi * 75 + h * 32;
        uint32_t* A32 = (uint32_t*)Atile;          // row stride 84 u32
        #pragma unroll
        for (int i = 0; i < 10; ++i) {
            int pe = t + i * 256;                  // < 2560 = 32m * 80 pairs
            int m = pe / 80, q32 = pe - m * 80;
            int kk = q32 * 2;
            float v0 = 0.f, v1 = 0.f;
            if (kk < 144) {
                int di = kk / 12, dj = kk - di * 12;
                v0 = gb[di * 75 + m + dj];
                int k1 = kk + 1, di1 = k1 / 12, dj1 = k1 - di1 * 12;
                v1 = gb[di1 * 75 + m + dj1];
            }
            A32[m * 84 + q32] = pack_bf(v0, v1);
        }
    }
    __syncthreads();

    // ---- q-matmul: qv2[mt][r] = {q(nt0), q(nt1)} in C/D layout ----
    f32x2 qv2[2][4];
    {
        short8_t bfq[2][5];
        #pragma unroll
        for (int nt = 0; nt < 2; ++nt)
            #pragma unroll
            for (int s = 0; s < 5; ++s)
                bfq[nt][s] = *(const short8_t*)&ATB[(nb + nt * 16 + col) * 160 + s * 32 + quad * 8];
        #pragma unroll
        for (int mt = 0; mt < 2; ++mt) {
            short8_t af[5];
            #pragma unroll
            for (int s = 0; s < 5; ++s)
                af[s] = *(const short8_t*)&Atile[(mt * 16 + col) * 168 + s * 32 + quad * 8];
            f32x4 acc0 = (f32x4){0.f, 0.f, 0.f, 0.f};
            f32x4 acc1 = (f32x4){0.f, 0.f, 0.f, 0.f};
            #pragma unroll
            for (int s = 0; s < 5; ++s) {
                acc0 = __builtin_amdgcn_mfma_f32_16x16x32_bf16(af[s], bfq[0][s], acc0, 0, 0, 0);
                acc1 = __builtin_amdgcn_mfma_f32_16x16x32_bf16(af[s], bfq[1][s], acc1, 0, 0, 0);
            }
            #pragma unroll
            for (int r = 0; r < 4; ++r) qv2[mt][r] = (f32x2){acc0[r], acc1[r]};
        }
    }

    // ---- X B-fragments: contiguous b128 from pre-permuted bf16 XPB ----
    short8_t xf[2][4];
    #pragma unroll
    for (int nt = 0; nt < 2; ++nt)
        #pragma unroll
        for (int s = 0; s < 4; ++s)
            xf[nt][s] = *(const short8_t*)&XPB[(nb + nt * 16 + col) * 128 + s * 32 + quad * 8];

    // ---- c0 / z0 init, seed Z (packed bf16 pairs from cfgb) ----
    uint32_t* Z32w = (uint32_t*)Zbuf[0];           // row stride 68 u32
    f32x2 cv2[2][4], zo2[2][4];
    #pragma unroll
    for (int mt = 0; mt < 2; ++mt)
        #pragma unroll
        for (int r = 0; r < 4; ++r) {
            int row = mt * 16 + quad * 4 + r;
            uint32_t pk = 0u;
            float c0 = 0.f, c1 = 0.f;
            if (!first) {
                pk = cfgb[(p0 + row) * 64 + 16 * w + col];
                c0 = bf2f((unsigned short)(pk & 0xFFFFu));
                c1 = bf2f((unsigned short)(pk >> 16));
            }
            cv2[mt][r] = (f32x2){c0, c1};
            zo2[mt][r] = (f32x2){c0, c1};
            Z32w[row * 68 + 16 * w + col] = pk;
        }
    __syncthreads();

    f32x4 acc[2][2];
    auto matmul = [&](const unsigned short* Zr) {
        short8_t af[2][4];
        #pragma unroll
        for (int mt = 0; mt < 2; ++mt)
            #pragma unroll
            for (int s = 0; s < 4; ++s)
                af[mt][s] = *(const short8_t*)&Zr[(mt * 16 + col) * 136 + s * 32 + quad * 8];
        #pragma unroll
        for (int mt = 0; mt < 2; ++mt)
            #pragma unroll
            for (int nt = 0; nt < 2; ++nt)
                acc[mt][nt] = (f32x4){0.f, 0.f, 0.f, 0.f};
        #pragma unroll
        for (int s = 0; s < 4; ++s)
            #pragma unroll
            for (int mt = 0; mt < 2; ++mt)
                #pragma unroll
                for (int nt = 0; nt < 2; ++nt)
                    acc[mt][nt] = __builtin_amdgcn_mfma_f32_16x16x32_bf16(
                        af[mt][s], xf[nt][s], acc[mt][nt], 0, 0, 0);
    };

    float tm = 1.0f;
    int cur = 0;
    #pragma unroll 1
    for (int it = 0; it < 14; ++it) {          // FISTA iters 1..14 (write z)
        matmul(Zbuf[cur]);
        float tnn = 0.5f * (1.0f + sqrtf(1.0f + 4.0f * tm * tm));
        float fm = (tm - 1.0f) / tnn;
        tm = tnn;
        f32x2 fm2 = (f32x2){fm, fm};
        uint32_t* Zw = (uint32_t*)Zbuf[cur ^ 1];
        #pragma unroll
        for (int mt = 0; mt < 2; ++mt)
            #pragma unroll
            for (int r = 0; r < 4; ++r) {
                f32x2 a2 = (f32x2){acc[mt][0][r], acc[mt][1][r]};
                f32x2 u2 = mu2 * (qv2[mt][r] - a2) + zo2[mt][r];
                f32x2 cl2 = __builtin_elementwise_min(
                                __builtin_elementwise_max(u2, nlam2), lam2);
                f32x2 cn2 = u2 - cl2;
                f32x2 zn2 = fm2 * (cn2 - cv2[mt][r]) + cn2;
                cv2[mt][r] = cn2;
                zo2[mt][r] = zn2;
                Zw[(mt * 16 + quad * 4 + r) * 68 + 16 * w + col] = pack_bf(zn2[0], zn2[1]);
            }
        __syncthreads();
        cur ^= 1;
    }
    {   // FISTA iter 15: compute c15; stage c15 (z15 never consumed)
        matmul(Zbuf[cur]);
        uint32_t* Zw = (uint32_t*)Zbuf[cur ^ 1];
        #pragma unroll
        for (int mt = 0; mt < 2; ++mt)
            #pragma unroll
            for (int r = 0; r < 4; ++r) {
                f32x2 a2 = (f32x2){acc[mt][0][r], acc[mt][1][r]};
                f32x2 u2 = mu2 * (qv2[mt][r] - a2) + zo2[mt][r];
                f32x2 cl2 = __builtin_elementwise_min(
                                __builtin_elementwise_max(u2, nlam2), lam2);
                f32x2 cn2 = u2 - cl2;
                cv2[mt][r] = cn2;
                Zw[(mt * 16 + quad * 4 + r) * 68 + 16 * w + col] = pack_bf(cn2[0], cn2[1]);
            }
        __syncthreads();
        cur ^= 1;
    }
    {   // final differentiable step: cf = prox(c15 + mu*(q - X@c15)); stage cf
        matmul(Zbuf[cur]);
        uint32_t* Zw = (uint32_t*)Zbuf[cur ^ 1];
        #pragma unroll
        for (int mt = 0; mt < 2; ++mt)
            #pragma unroll
            for (int r = 0; r < 4; ++r) {
                int row = mt * 16 + quad * 4 + r;
                f32x2 a2 = (f32x2){acc[mt][0][r], acc[mt][1][r]};
                f32x2 u2 = mu2 * (qv2[mt][r] - a2) + cv2[mt][r];
                f32x2 cl2 = __builtin_elementwise_min(
                                __builtin_elementwise_max(u2, nlam2), lam2);
                f32x2 cf2 = u2 - cl2;
                uint32_t pk = pack_bf(cf2[0], cf2[1]);
                if (write_cf) cfgb[(p0 + row) * 64 + 16 * w + col] = pk;
                Zw[row * 68 + 16 * w + col] = pk;
            }
        __syncthreads();
        cur ^= 1;
    }

    // ---- pred tail: predh[32][144] = bf16(cf @ atoms_n + pm) ----
    {
        int jt0 = (w == 0) ? 0 : (2 * w + 1);
        int jtn = (w == 0) ? 3 : 2;
        const unsigned short* Zr = Zbuf[cur];
        short8_t af[2][4];
        #pragma unroll
        for (int mt = 0; mt < 2; ++mt)
            #pragma unroll
            for (int s = 0; s < 4; ++s)
                af[mt][s] = *(const short8_t*)&Zr[(mt * 16 + col) * 136 + s * 32 + quad * 8];
        f32x4 accp[2][3];
        #pragma unroll
        for (int mt = 0; mt < 2; ++mt)
            #pragma unroll
            for (int ji = 0; ji < 3; ++ji)
                accp[mt][ji] = (f32x4){0.f, 0.f, 0.f, 0.f};
        #pragma unroll
        for (int ji = 0; ji < 3; ++ji) {
            if (ji < jtn) {
                int jt = jt0 + ji;
                short8_t bf4[4];
                #pragma unroll
                for (int s = 0; s < 4; ++s)
                    bf4[s] = *(const short8_t*)&ANTBP[(jt * 16 + col) * 128 + s * 32 + quad * 8];
                #pragma unroll
                for (int mt = 0; mt < 2; ++mt)
                    #pragma unroll
                    for (int s = 0; s < 4; ++s)
                        accp[mt][ji] = __builtin_amdgcn_mfma_f32_16x16x32_bf16(
                            af[mt][s], bf4[s], accp[mt][ji], 0, 0, 0);
            }
        }
        #pragma unroll
        for (int mt = 0; mt < 2; ++mt)
            #pragma unroll
            for (int r = 0; r < 4; ++r) {
                int p = p0 + mt * 16 + quad * 4 + r;
                float pmv = pm[p];
                #pragma unroll
                for (int ji = 0; ji < 3; ++ji)
                    if (ji < jtn)
                        predh[p * 144 + (jt0 + ji) * 16 + col] = f2bh(accp[mt][ji][r] + pmv);
            }
    }
}

// ---- fold via LDS staging: block = (output row i, batch b); bf16 pred reads. ----
__global__ __launch_bounds__(256) void k_fold(const float* y, const float* beta_p,
                                              const unsigned short* predh, float* goal,
                                              float* out, int write_out) {
    __shared__ float P[12 * 832];              // 39,936 B
    int i = blockIdx.x, b = blockIdx.y;
    int t = threadIdx.x;
    for (int di = 0; di < 12; ++di) {
        int pi = i - di;
        if ((unsigned)pi >= 64u) continue;     // uniform per block
        int base = (b << 12) + (pi << 6);
        #pragma unroll
        for (int it = 0; it < 3; ++it) {
            int e = t + it * 256;              // < 768 = 64 pj * 12 dj
            int pj = e / 12, dj = e - pj * 12;
            P[di * 832 + pj * 13 + dj] = bf2f(predh[(base + pj) * AA + di * 12 + dj]);
        }
    }
    __syncthreads();
    if (t >= 75) return;
    int j = t;
    float S = 0.f;
    for (int di = 0; di < 12; ++di) {
        if ((unsigned)(i - di) >= 64u) continue;
        const float* Pd = &P[di * 832];
        #pragma unroll
        for (int dj = 0; dj < 12; ++dj) {
            int pj = j - dj;
            if ((unsigned)pj >= 64u) continue;
            S += Pd[pj * 13 + dj];
        }
    }
    int ci = min(i, 11) - max(i - 63, 0) + 1;
    int cj = min(j, 11) - max(j - 63, 0) + 1;
    float beta = fmaxf(beta_p[0], 0.0f);
    int idx = i * 75 + j;
    float yv = y[b * 5625 + idx];
    float g = (yv + beta * S) / (1.0f + beta * (float)(ci * cj));
    if (write_out) out[b * 5625 + idx] = g;
    else           goal[b * 5625 + idx] = g;
}

extern "C" void kernel_launch(void* const* d_in, const int* in_sizes, int n_in,
                              void* d_out, int out_size, void* d_ws, size_t ws_size,
                              hipStream_t stream) {
    const float* y     = (const float*)d_in[0];
    const float* atoms = (const float*)d_in[1];
    const float* beta  = (const float*)d_in[2];
    const float* mu    = (const float*)d_in[3];
    float* out = (float*)d_out;
    float* ws = (float*)d_ws;

    k_setup<<<46, 1024, 0, stream>>>(atoms, mu, ws, y);   // block0 chain + workers goal/pm
    k_finalize<<<216, 256, 0, stream>>>(ws);              // XPB + ATB + ANTBP

    for (int u = 0; u < 2; ++u) {
        k_fista<<<1024, 256, 0, stream>>>((const unsigned short*)(ws + OFS_X),
                                          ws + OFS_GOAL,
                                          (const unsigned short*)(ws + OFS_ATB),
                                          (const unsigned short*)(ws + OFS_ANTB),
                                          ws + OFS_PM, (uint32_t*)(ws + OFS_CF),
                                          (unsigned short*)(ws + OFS_PRED),
                                          mu, u == 0 ? 1 : 0, u == 0 ? 1 : 0);
        k_fold<<<dim3(75, 8), 256, 0, stream>>>(y, beta,
                                                (const unsigned short*)(ws + OFS_PRED),
                                                ws + OFS_GOAL, out, u == 1 ? 1 : 0);
    }
}